// Round 15
// baseline (1808.340 us; speedup 1.0000x reference)
//
#include <hip/hip_runtime.h>
#include <math.h>

#define B_ 512
#define W_ 64
#define D_ 512
#define H_ 1024
#define NC_ 1024
#define K_ 8
#define C_ 64
#define BN_ 512
#define G3 (3*H_)

typedef unsigned short u16;
typedef __attribute__((ext_vector_type(8))) short bf16x8;
typedef __attribute__((ext_vector_type(4))) float f32x4;

__device__ __forceinline__ float bf_up(u16 h) { return __uint_as_float(((unsigned)h) << 16); }
__device__ __forceinline__ u16 bf_rn(float x) {
    unsigned u = __float_as_uint(x);
    return (u16)((u + 0x7FFFu + ((u >> 16) & 1u)) >> 16);
}

__device__ __forceinline__ void split8v(float4 x, float4 y, uint4& H, uint4& L) {
    float v[8] = {x.x, x.y, x.z, x.w, y.x, y.y, y.z, y.w};
    union { u16 s[8]; uint4 u; } Hh, Ll;
    #pragma unroll
    for (int i = 0; i < 8; ++i) {
        unsigned ub = __float_as_uint(v[i]);
        u16 hi = (u16)(ub >> 16);
        Hh.s[i] = hi;
        Ll.s[i] = bf_rn(v[i] - bf_up(hi));
    }
    H = Hh.u; L = Ll.u;
}

__device__ __forceinline__ void cvt_store8(u16* ph, u16* pl, float4 x, float4 y) {
    uint4 H, L; split8v(x, y, H, L);
    *(uint4*)ph = H;
    *(uint4*)pl = L;
}

struct GArgs {
    const float* A;  long lda;
    const float* Bw;
    const u16* Bhi;  const u16* Blo;
    const float* bias;
    float* C;  long ldc;
    int K;
};

// ---- generic hi/lo GEMM (tail GEMMs + fallback), M64xN64, BK=32 ----
template<int ACT, int BPRE>
__device__ __forceinline__ void gemm_core64(const GArgs g, int bx, int by, u16* lds)
{
    u16* Ah = lds;
    u16* Al = lds + 2560;
    u16* Bh = lds + 5120;
    u16* Bl = lds + 7680;
    const int tid = threadIdx.x;
    const int l = tid & 63, wv = tid >> 6;
    const int m0 = by * 64, n0 = bx * 64;
    const int sr = tid >> 2, sc = (tid & 3) * 8;
    const int sA = sr * 40 + sc;

    const float* Ap = g.A + (long)(m0 + sr) * g.lda + sc;
    const float* Bp = 0; const u16 *Bph = 0, *Bpl = 0;
    if (BPRE) { Bph = g.Bhi + (long)(n0 + sr) * g.K + sc; Bpl = g.Blo + (long)(n0 + sr) * g.K + sc; }
    else      { Bp  = g.Bw  + (long)(n0 + sr) * g.K + sc; }

    f32x4 acc[4] = {};

    for (int k0 = 0; k0 < g.K; k0 += 32) {
        float4 a0 = *(const float4*)(Ap + k0);
        float4 a1 = *(const float4*)(Ap + k0 + 4);
        float4 b0, b1; uint4 h0, l0;
        if (BPRE) { h0 = *(const uint4*)(Bph + k0); l0 = *(const uint4*)(Bpl + k0); }
        else      { b0 = *(const float4*)(Bp + k0); b1 = *(const float4*)(Bp + k0 + 4); }
        __syncthreads();
        cvt_store8(Ah + sA, Al + sA, a0, a1);
        if (BPRE) { *(uint4*)(Bh + sA) = h0; *(uint4*)(Bl + sA) = l0; }
        else      { cvt_store8(Bh + sA, Bl + sA, b0, b1); }
        __syncthreads();

        const int fr = (l & 15) * 40 + (l >> 4) * 8;
        bf16x8 bh = *(const bf16x8*)(Bh + wv * 640 + fr);
        bf16x8 bl = *(const bf16x8*)(Bl + wv * 640 + fr);
        #pragma unroll
        for (int mt = 0; mt < 4; ++mt) {
            bf16x8 ah = *(const bf16x8*)(Ah + mt * 640 + fr);
            bf16x8 al = *(const bf16x8*)(Al + mt * 640 + fr);
            acc[mt] = __builtin_amdgcn_mfma_f32_16x16x32_bf16(ah, bh, acc[mt], 0, 0, 0);
            acc[mt] = __builtin_amdgcn_mfma_f32_16x16x32_bf16(ah, bl, acc[mt], 0, 0, 0);
            acc[mt] = __builtin_amdgcn_mfma_f32_16x16x32_bf16(al, bh, acc[mt], 0, 0, 0);
        }
    }

    const int n = n0 + wv * 16 + (l & 15);
    const float bv = g.bias[n];
    #pragma unroll
    for (int mt = 0; mt < 4; ++mt) {
        #pragma unroll
        for (int r = 0; r < 4; ++r) {
            int m = m0 + mt * 16 + (l >> 4) * 4 + r;
            float v = acc[mt][r] + bv;
            if (ACT == 1) v = v / (1.f + expf(-v));
            g.C[(long)m * g.ldc + n] = v;
        }
    }
}

template<int ACT, int BPRE>
__global__ __launch_bounds__(256)
void hilo_gemm64(GArgs g) {
    __shared__ u16 lds[10240];
    gemm_core64<ACT, BPRE>(g, blockIdx.x, blockIdx.y, lds);
}

// =================== round-15: fused GRU step, A via LDS, B direct global->reg ===================
// Frag planes: plane[((frag*NKC + kc)*64 + lane)*8 + s], lane=(row&15)+((k&31)>>3)*16, s=k&7.
// 512 blocks x 256 thr. Tile 32m x 96n. Waves: mh=wv&1 (1 m-frag), nh=wv>>1 (48-col gate triple).
// Stages 0..15: gi (x@wih48, NKC=16). Stages 16..47: gh (h@whh48, NKC=32).
// A staged in dbuf LDS (4KB ea); B loaded per-wave direct to named regs, depth-2 prefetch.
struct FS6 {
    const u16* hFh_in; const u16* hFl_in;
    u16* hFh_out; u16* hFl_out;
    float* h_f32_out;                  // null except last step
    const u16* WFh; const u16* WFl;    // whh 48-perm frag, NKC=32
    const u16* XWh; const u16* XWl;    // wih 48-perm frag, NKC=16
    const u16* xFh; const u16* xFl;    // x slice w planes
    const float* b_hh; const float* b_ih;
};

__global__ __launch_bounds__(256)
void gru_step9(FS6 f)
{
    __shared__ u16 lds[4096];   // 2 x 2048 u16: [AH 1024 | AL 1024]
    const int tid = threadIdx.x, l = tid & 63, wv = tid >> 6;
    const int mh = wv & 1, nh = wv >> 1;
    const int by = blockIdx.x >> 5, bx = blockIdx.x & 31;

    // A chunk: 256 threads cover 2 mf x 2 planes x 64 lanes
    const int t0 = tid >> 6;
    const int mf0 = t0 & 1, pl0 = t0 >> 1;
    const u16* giP0 = (pl0 ? f.xFl : f.xFh) + (long)(by * 2 + mf0) * (16 * 512) + (long)l * 8;
    const u16* ghP0 = (pl0 ? f.hFl_in : f.hFh_in) + (long)(by * 2 + mf0) * (32 * 512) + (long)l * 8;
    const int lo0 = pl0 * 1024 + (mf0 * 64 + l) * 8;

    // B bases for this wave's gate triple (nf stride: NKC*512 u16; kc stride 512)
    const long nfb = (long)(bx * 6 + nh * 3);
    const u16* bGIh = f.XWh + nfb * 8192 + (long)l * 8;
    const u16* bGIl = f.XWl + nfb * 8192 + (long)l * 8;
    const u16* bGHh = f.WFh + nfb * 16384 + (long)l * 8;
    const u16* bGHl = f.WFl + nfb * 16384 + (long)l * 8;

    f32x4 gi0 = {}, gi1 = {}, gi2 = {}, gh0 = {}, gh1 = {}, gh2 = {};

    #define LDRA9(st, R) { \
        if ((st) >= 16) R = *(const uint4*)(ghP0 + (long)((st) - 16) * 512); \
        else            R = *(const uint4*)(giP0 + (long)(st) * 512); }

    #define WRLA9(bi, R) { *(uint4*)(lds + (bi) * 2048 + lo0) = R; }

    #define LDRB9(st, B0h, B1h, B2h, B0l, B1l, B2l) { \
        if ((st) >= 16) { long ko = (long)((st) - 16) * 512; \
            B0h = *(const uint4*)(bGHh + ko);          B1h = *(const uint4*)(bGHh + 16384 + ko); \
            B2h = *(const uint4*)(bGHh + 32768 + ko); \
            B0l = *(const uint4*)(bGHl + ko);          B1l = *(const uint4*)(bGHl + 16384 + ko); \
            B2l = *(const uint4*)(bGHl + 32768 + ko); \
        } else { long ko = (long)(st) * 512; \
            B0h = *(const uint4*)(bGIh + ko);          B1h = *(const uint4*)(bGIh + 8192 + ko); \
            B2h = *(const uint4*)(bGIh + 16384 + ko); \
            B0l = *(const uint4*)(bGIl + ko);          B1l = *(const uint4*)(bGIl + 8192 + ko); \
            B2l = *(const uint4*)(bGIl + 16384 + ko); } }

    #define CMP9(st, B0h, B1h, B2h, B0l, B1l, B2l) { \
        const u16* bb_ = lds + ((st) & 1) * 2048; \
        bf16x8 ah = *(const bf16x8*)(bb_ + (mh * 64 + l) * 8); \
        bf16x8 al = *(const bf16x8*)(bb_ + 1024 + (mh * 64 + l) * 8); \
        bf16x8 c0h = *(const bf16x8*)&B0h; bf16x8 c1h = *(const bf16x8*)&B1h; bf16x8 c2h = *(const bf16x8*)&B2h; \
        bf16x8 c0l = *(const bf16x8*)&B0l; bf16x8 c1l = *(const bf16x8*)&B1l; bf16x8 c2l = *(const bf16x8*)&B2l; \
        if ((st) < 16) { \
            gi0 = __builtin_amdgcn_mfma_f32_16x16x32_bf16(ah, c0h, gi0, 0, 0, 0); \
            gi0 = __builtin_amdgcn_mfma_f32_16x16x32_bf16(ah, c0l, gi0, 0, 0, 0); \
            gi0 = __builtin_amdgcn_mfma_f32_16x16x32_bf16(al, c0h, gi0, 0, 0, 0); \
            gi1 = __builtin_amdgcn_mfma_f32_16x16x32_bf16(ah, c1h, gi1, 0, 0, 0); \
            gi1 = __builtin_amdgcn_mfma_f32_16x16x32_bf16(ah, c1l, gi1, 0, 0, 0); \
            gi1 = __builtin_amdgcn_mfma_f32_16x16x32_bf16(al, c1h, gi1, 0, 0, 0); \
            gi2 = __builtin_amdgcn_mfma_f32_16x16x32_bf16(ah, c2h, gi2, 0, 0, 0); \
            gi2 = __builtin_amdgcn_mfma_f32_16x16x32_bf16(ah, c2l, gi2, 0, 0, 0); \
            gi2 = __builtin_amdgcn_mfma_f32_16x16x32_bf16(al, c2h, gi2, 0, 0, 0); \
        } else { \
            gh0 = __builtin_amdgcn_mfma_f32_16x16x32_bf16(ah, c0h, gh0, 0, 0, 0); \
            gh0 = __builtin_amdgcn_mfma_f32_16x16x32_bf16(ah, c0l, gh0, 0, 0, 0); \
            gh0 = __builtin_amdgcn_mfma_f32_16x16x32_bf16(al, c0h, gh0, 0, 0, 0); \
            gh1 = __builtin_amdgcn_mfma_f32_16x16x32_bf16(ah, c1h, gh1, 0, 0, 0); \
            gh1 = __builtin_amdgcn_mfma_f32_16x16x32_bf16(ah, c1l, gh1, 0, 0, 0); \
            gh1 = __builtin_amdgcn_mfma_f32_16x16x32_bf16(al, c1h, gh1, 0, 0, 0); \
            gh2 = __builtin_amdgcn_mfma_f32_16x16x32_bf16(ah, c2h, gh2, 0, 0, 0); \
            gh2 = __builtin_amdgcn_mfma_f32_16x16x32_bf16(ah, c2l, gh2, 0, 0, 0); \
            gh2 = __builtin_amdgcn_mfma_f32_16x16x32_bf16(al, c2h, gh2, 0, 0, 0); \
        } }

    uint4 a0, b0;
    uint4 sB0h, sB1h, sB2h, sB0l, sB1l, sB2l;    // B for even stages
    uint4 tB0h, tB1h, tB2h, tB0l, tB1l, tB2l;    // B for odd stages
    LDRA9(0, a0); WRLA9(0, a0);
    LDRA9(1, a0);
    LDRA9(2, b0);
    LDRB9(0, sB0h, sB1h, sB2h, sB0l, sB1l, sB2l);
    LDRB9(1, tB0h, tB1h, tB2h, tB0l, tB1l, tB2l);
    __syncthreads();
    #pragma unroll
    for (int s2 = 0; s2 < 48; s2 += 2) {
        CMP9(s2, sB0h, sB1h, sB2h, sB0l, sB1l, sB2l);
        WRLA9(1, a0);
        if (s2 + 3 < 48) LDRA9(s2 + 3, a0);
        if (s2 + 2 < 48) LDRB9(s2 + 2, sB0h, sB1h, sB2h, sB0l, sB1l, sB2l);
        __syncthreads();
        CMP9(s2 + 1, tB0h, tB1h, tB2h, tB0l, tB1l, tB2l);
        if (s2 + 2 < 48) WRLA9(0, b0);
        if (s2 + 4 < 48) LDRA9(s2 + 4, b0);
        if (s2 + 3 < 48) LDRB9(s2 + 3, tB0h, tB1h, tB2h, tB0l, tB1l, tB2l);
        __syncthreads();
    }
    #undef LDRA9
    #undef WRLA9
    #undef LDRB9
    #undef CMP9

    // ---- fused GRU update epilogue ----
    const int mfG = by * 2 + mh;
    const int j = (bx * 2 + nh) * 16 + (l & 15);
    const float bir = f.b_ih[j], biz = f.b_ih[H_ + j], bin2 = f.b_ih[2 * H_ + j];
    const float bhr = f.b_hh[j], bhz = f.b_hh[H_ + j], bhn = f.b_hh[2 * H_ + j];
    const int kcj = j >> 5, laneTop = ((j >> 3) & 3) * 16, sj = j & 7;
    const long foB = ((long)(mfG * 32 + kcj) * 64) * 8 + sj;
    const bool wf32 = (f.h_f32_out != nullptr);
    #pragma unroll
    for (int r = 0; r < 4; ++r) {
        int mlow = (l >> 4) * 4 + r;          // m & 15
        long fo = foB + (long)(mlow + laneTop) * 8;
        float hprev = bf_up(f.hFh_in[fo]) + bf_up(f.hFl_in[fo]);
        float ir = gi0[r] + bir, iz = gi1[r] + biz, inn = gi2[r] + bin2;
        float hr = gh0[r] + bhr, hz = gh1[r] + bhz, hn = gh2[r] + bhn;
        float rg = 1.f / (1.f + expf(-(ir + hr)));
        float zg = 1.f / (1.f + expf(-(iz + hz)));
        float ng = tanhf(inn + rg * hn);
        float hv = (1.f - zg) * ng + zg * hprev;
        unsigned ub = __float_as_uint(hv);
        u16 hh = (u16)(ub >> 16);
        f.hFh_out[fo] = hh;
        f.hFl_out[fo] = bf_rn(hv - bf_up(hh));
        if (wf32) {
            int m = by * 32 + mh * 16 + mlow;
            f.h_f32_out[(long)m * H_ + j] = hv;
        }
    }
}

// ---------------- prep kernels ----------------
__global__ __launch_bounds__(256)
void to_hilo(const float* __restrict__ src, u16* __restrict__ hi, u16* __restrict__ lo, long n8) {
    long i = (long)blockIdx.x * 256 + threadIdx.x;
    if (i >= n8) return;
    float4 a = ((const float4*)src)[2 * i];
    float4 b = ((const float4*)src)[2 * i + 1];
    uint4 H, L; split8v(a, b, H, L);
    ((uint4*)hi)[i] = H;
    ((uint4*)lo)[i] = L;
}

// W [3H x KD] -> frag order with 48-perm: frag col p = nf*16+(l&15); src row = g*H + jg*16 + jl
template<int KD, int NKC>
__global__ __launch_bounds__(256)
void prep_w48(const float* __restrict__ W, u16* __restrict__ fh, u16* __restrict__ fl)
{
    long t = (long)blockIdx.x * 256 + threadIdx.x;   // 192*NKC*64 total
    if (t >= (long)192 * NKC * 64) return;
    int l = (int)(t & 63);
    long nk = t >> 6;
    int kc = (int)(nk % NKC);
    int nf = (int)(nk / NKC);
    int p = nf * 16 + (l & 15);
    int jg = p / 48, g = (p % 48) >> 4, jl = p & 15;
    int srow = g * H_ + jg * 16 + jl;
    int k0 = kc * 32 + (l >> 4) * 8;
    float4 v0 = *(const float4*)(W + (long)srow * KD + k0);
    float4 v1 = *(const float4*)(W + (long)srow * KD + k0 + 4);
    uint4 H, L; split8v(v0, v1, H, L);
    ((uint4*)fh)[t] = H;
    ((uint4*)fl)[t] = L;
}

// pack ALL x slices: each wave writes a contiguous 1KB frag-plane run (coalesced stores)
__global__ __launch_bounds__(256)
void pack_x_all(const float* __restrict__ x, u16* __restrict__ dh, u16* __restrict__ dl)
{
    const int tid = threadIdx.x;
    const int lane_lo = tid & 15, sel = (tid >> 4) & 3;
    #pragma unroll
    for (int it = 0; it < 4; ++it) {
        int g = blockIdx.x * 16 + it * 4 + (tid >> 6);   // 32768 groups
        int mf = g & 31, kc = (g >> 5) & 15, w = g >> 9;
        int b = mf * 16 + lane_lo;
        int dd = kc * 32 + sel * 8;
        int lane = lane_lo + sel * 16;
        const float* src = x + (long)b * (W_ * D_) + (long)w * D_ + dd;
        float4 v0 = *(const float4*)src;
        float4 v1 = *(const float4*)(src + 4);
        uint4 H, L; split8v(v0, v1, H, L);
        long fo = (long)w * 262144 + ((long)(mf * 16 + kc) * 64 + lane) * 8;
        *(uint4*)(dh + fo) = H;
        *(uint4*)(dl + fo) = L;
    }
}

// =================== legacy fallback (fp32-direct) ===================
struct StepArgs {
    const float* h_in;  float* h_out;
    const float* W_hh;
    const float* gi;
    const float* b_hh;
    const float* xw;
    const float* W_ih;
    const float* b_ih;
    float* gi_out;
};

__global__ __launch_bounds__(256)
void gru_step2(StepArgs s)
{
    __shared__ u16 lds[17920];
    const int id = blockIdx.x;
    const int tid = threadIdx.x;
    if (id >= 256) {
        if (!s.xw) return;
        int id2 = id - 256;
        GArgs g;
        g.A = s.xw; g.lda = (long)W_ * D_;
        g.Bw = s.W_ih; g.Bhi = 0; g.Blo = 0;
        g.bias = s.b_ih; g.C = s.gi_out; g.ldc = G3; g.K = D_;
        gemm_core64<0, 0>(g, id2 % 48, id2 / 48, lds);
        return;
    }
    u16* Ah = lds;
    u16* Al = lds + 1280;
    u16* Bh = lds + 2560;
    u16* Bl = lds + 10240;
    const int by = id >> 4, bx = id & 15;
    const int l = tid & 63, wv = tid >> 6;
    const int m0 = by * 32, j0 = bx * 64;
    const int sr = tid >> 2, sc = (tid & 3) * 8;
    const int sA = sr * 40 + sc;

    const float* Ap = s.h_in + (long)(m0 + (tid >> 2)) * H_ + sc;

    f32x4 acc[2][3] = {};

    for (int k0 = 0; k0 < H_; k0 += 32) {
        float4 a0, a1;
        if (tid < 128) {
            a0 = *(const float4*)(Ap + k0);
            a1 = *(const float4*)(Ap + k0 + 4);
        }
        float4 bf0[3], bf1[3];
        #pragma unroll
        for (int g = 0; g < 3; ++g) {
            long rowp = (long)(g * H_ + j0 + sr);
            bf0[g] = *(const float4*)(s.W_hh + rowp * H_ + k0 + sc);
            bf1[g] = *(const float4*)(s.W_hh + rowp * H_ + k0 + sc + 4);
        }
        __syncthreads();
        if (tid < 128) cvt_store8(Ah + sA, Al + sA, a0, a1);
        #pragma unroll
        for (int g = 0; g < 3; ++g)
            cvt_store8(Bh + g * 2560 + sA, Bl + g * 2560 + sA, bf0[g], bf1[g]);
        __syncthreads();

        const int fr = (l & 15) * 40 + (l >> 4) * 8;
        bf16x8 bhf[3], blf[3];
        #pragma unroll
        for (int g = 0; g < 3; ++g) {
            bhf[g] = *(const bf16x8*)(Bh + g * 2560 + wv * 640 + fr);
            blf[g] = *(const bf16x8*)(Bl + g * 2560 + wv * 640 + fr);
        }
        #pragma unroll
        for (int mt = 0; mt < 2; ++mt) {
            bf16x8 ah = *(const bf16x8*)(Ah + mt * 640 + fr);
            bf16x8 al = *(const bf16x8*)(Al + mt * 640 + fr);
            #pragma unroll
            for (int g = 0; g < 3; ++g) {
                acc[mt][g] = __builtin_amdgcn_mfma_f32_16x16x32_bf16(ah, bhf[g], acc[mt][g], 0, 0, 0);
                acc[mt][g] = __builtin_amdgcn_mfma_f32_16x16x32_bf16(ah, blf[g], acc[mt][g], 0, 0, 0);
                acc[mt][g] = __builtin_amdgcn_mfma_f32_16x16x32_bf16(al, bhf[g], acc[mt][g], 0, 0, 0);
            }
        }
    }

    const int j = j0 + wv * 16 + (l & 15);
    const float bhr = s.b_hh[j], bhz = s.b_hh[H_ + j], bhn = s.b_hh[2 * H_ + j];
    #pragma unroll
    for (int mt = 0; mt < 2; ++mt) {
        #pragma unroll
        for (int r = 0; r < 4; ++r) {
            int m = m0 + mt * 16 + (l >> 4) * 4 + r;
            const float* gib = s.gi + (long)m * G3;
            float ir = gib[j], iz = gib[H_ + j], inn = gib[2 * H_ + j];
            float hr = acc[mt][0][r] + bhr;
            float hz = acc[mt][1][r] + bhz;
            float hn = acc[mt][2][r] + bhn;
            float rg = 1.f / (1.f + expf(-(ir + hr)));
            float zg = 1.f / (1.f + expf(-(iz + hz)));
            float ng = tanhf(inn + rg * hn);
            s.h_out[(long)m * H_ + j] = (1.f - zg) * ng + zg * s.h_in[(long)m * H_ + j];
        }
    }
}

// ---------------- misc small kernels ----------------
__global__ void emb_norm(const float* __restrict__ emb, float* __restrict__ e2,
                         float* __restrict__ loss_slot)
{
    int n = blockIdx.x * 256 + threadIdx.x;
    if (n == 0) *loss_slot = 0.f;
    if (n < NC_) {
        const float4* e4 = (const float4*)(emb + (long)n * C_);
        float s = 0.f;
        #pragma unroll
        for (int c = 0; c < 16; ++c) { float4 e = e4[c]; s += e.x*e.x + e.y*e.y + e.z*e.z + e.w*e.w; }
        e2[n] = s;
    }
}

__global__ __launch_bounds__(256)
void vq16(const float* __restrict__ q, const float* __restrict__ emb,
          const float* __restrict__ e2, float* __restrict__ out_f,
          int* __restrict__ out_i)
{
    __shared__ float es[128 * 68];
    const int blk = blockIdx.x, tid = threadIdx.x;
    const int qg = tid >> 4, sI = tid & 15;
    float4 qr[16];
    {
        const float4* qrow = (const float4*)(q + (long)(blk * 16 + qg) * C_);
        #pragma unroll
        for (int i = 0; i < 16; ++i) qr[i] = qrow[i];
    }
    float bestv = 3.4e38f; int besti = 0;

    for (int n0 = 0; n0 < NC_; n0 += 128) {
        __syncthreads();
        const float4* e4 = (const float4*)(emb + (long)n0 * C_);
        #pragma unroll
        for (int i = tid; i < 2048; i += 256) {
            int code = i >> 4, c4 = i & 15;
            *(float4*)(es + code * 68 + c4 * 4) = e4[i];
        }
        __syncthreads();
        #pragma unroll
        for (int jj = 0; jj < 8; ++jj) {
            int code = sI + 16 * jj;
            const float* er = es + code * 68;
            float dot = 0.f;
            #pragma unroll
            for (int c4 = 0; c4 < 16; ++c4) {
                float4 ev = *(const float4*)(er + c4 * 4);
                dot += ev.x * qr[c4].x + ev.y * qr[c4].y + ev.z * qr[c4].z + ev.w * qr[c4].w;
            }
            float d = e2[n0 + code] - 2.f * dot;
            if (d < bestv) { bestv = d; besti = n0 + code; }
        }
    }
    #pragma unroll
    for (int m = 1; m <= 8; m <<= 1) {
        float ov = __shfl_xor(bestv, m);
        int   oi = __shfl_xor(besti, m);
        if (ov < bestv || (ov == bestv && oi < besti)) { bestv = ov; besti = oi; }
    }
    if (sI == 0) {
        int bk = blk * 16 + qg;
        out_f[bk] = (float)besti;
        out_i[bk] = besti;
    }
}

__global__ __launch_bounds__(256)
void gather_loss(const float* __restrict__ q, const float* __restrict__ emb,
                 const int* __restrict__ idx, float* __restrict__ quant_out,
                 float* __restrict__ narr_out, float* __restrict__ loss_slot)
{
    int i = blockIdx.x * 256 + threadIdx.x;
    int bk = i >> 6;
    int c  = i & 63;
    float e  = emb[(long)idx[bk] * C_ + c];
    float qv = q[i];
    quant_out[i] = e;
    narr_out[i]  = e;
    float dsq = (qv - e) * (qv - e);
    __shared__ float red[256];
    red[threadIdx.x] = dsq;
    __syncthreads();
    for (int s = 128; s > 0; s >>= 1) {
        if (threadIdx.x < s) red[threadIdx.x] += red[threadIdx.x + s];
        __syncthreads();
    }
    if (threadIdx.x == 0)
        atomicAdd(loss_slot, red[0] * (1.25f / (float)(B_ * K_ * C_)));
}

__global__ __launch_bounds__(256)
void build_uin(const float* __restrict__ x, const float* __restrict__ narr,
               float* __restrict__ uin)
{
    int i = blockIdx.x * 256 + threadIdx.x;
    int b = i >> 10;
    int j = i & 1023;
    uin[i] = (j < D_) ? x[(long)b * W_ * D_ + (long)(W_ - 1) * D_ + j]
                      : narr[(long)b * BN_ + (j - D_)];
}

__global__ __launch_bounds__(256)
void copy_f(const float* __restrict__ src, float* __restrict__ dst)
{
    int i = blockIdx.x * 256 + threadIdx.x;
    dst[i] = src[i];
}

extern "C" void kernel_launch(void* const* d_in, const int* in_sizes, int n_in,
                              void* d_out, int out_size, void* d_ws, size_t ws_size,
                              hipStream_t stream)
{
    (void)in_sizes; (void)n_in; (void)out_size;
    const float* x     = (const float*)d_in[0];
    const float* W_ih  = (const float*)d_in[1];
    const float* W_hh  = (const float*)d_in[2];
    const float* b_ih  = (const float*)d_in[3];
    const float* b_hh  = (const float*)d_in[4];
    const float* Wq    = (const float*)d_in[5];
    const float* bq    = (const float*)d_in[6];
    const float* emb   = (const float*)d_in[7];
    const float* uW1   = (const float*)d_in[8];
    const float* ub1   = (const float*)d_in[9];
    const float* uW2   = (const float*)d_in[10];
    const float* ub2   = (const float*)d_in[11];
    const float* pW1   = (const float*)d_in[12];
    const float* pb1   = (const float*)d_in[13];
    const float* pW2   = (const float*)d_in[14];
    const float* pb2   = (const float*)d_in[15];

    float* ws = (float*)d_ws;
    float* hA   = ws;                       // 524288
    float* giA  = ws + 524288;              // 1572864 (fallback only)
    float* giB  = ws + 2097152;             // 1572864 (fallback only)
    float* q    = ws + 3670016;             // 262144
    float* e2   = ws + 3932160;             // 1024
    int*   idxi = (int*)(ws + 3933184);     // 4096
    const long FLOAT_WORDS = 3937280;
    float* uin  = giB;
    float* mlph = giB + 524288;
    float* t1   = giA;

    u16* wsu = (u16*)((char*)d_ws + FLOAT_WORDS * sizeof(float));
    // frag-ordered GRU weights (48-perm)
    u16* whhF_h = wsu;             u16* whhF_l = wsu + 3145728;
    u16* wihF_h = wsu + 6291456;   u16* wihF_l = wsu + 7864320;
    // row-major tail weights
    u16* wqR_h  = wsu + 9437184;   u16* wqR_l  = wsu + 9961472;
    u16* uw1R_h = wsu + 10485760;  u16* uw1R_l = wsu + 11534336;
    u16* uw2R_h = wsu + 12582912;  u16* uw2R_l = wsu + 13631488;
    u16* pw1R_h = wsu + 14680064;  u16* pw1R_l = wsu + 15204352;
    u16* pw2R_h = wsu + 15728640;  u16* pw2R_l = wsu + 16252928;
    // h frag planes (ping-pong)
    u16* hF_h[2] = { wsu + 16777216, wsu + 17301504 };
    u16* hF_l[2] = { wsu + 17825792, wsu + 18350080 };
    // x frag planes, all 64 slices
    u16* xF_h = wsu + 18874368;    // 16777216
    u16* xF_l = wsu + 35651584;    // 16777216
    const size_t NEED_NEW = FLOAT_WORDS * sizeof(float) + (size_t)52428800 * 2;
    const bool fast = ws_size >= NEED_NEW;

    float* out = (float*)d_out;
    const long o_idx   = 0;
    const long o_quant = o_idx   + (long)B_ * K_;
    const long o_narr  = o_quant + (long)B_ * K_ * C_;
    const long o_unc   = o_narr  + (long)B_ * BN_;
    const long o_pred  = o_unc   + (long)B_ * H_;
    const long o_loss  = o_pred  + (long)B_ * BN_;
    const long o_lh    = o_loss  + 1;

    float* hB = out + o_unc;                 // fallback ping-pong only
    float* hbuf[2] = { hA, hB };
    float* gibuf[2] = { giA, giB };

    hipMemsetAsync(hA, 0, (size_t)B_ * H_ * sizeof(float), stream);
    emb_norm<<<4, 256, 0, stream>>>(emb, e2, out + o_loss);

    auto mkargs = [&](const float* A, long lda, const float* Bw, const u16* Bh, const u16* Bl,
                      const float* bias, float* C, long ldc, int Kd) {
        GArgs g; g.A = A; g.lda = lda; g.Bw = Bw; g.Bhi = Bh; g.Blo = Bl;
        g.bias = bias; g.C = C; g.ldc = ldc; g.K = Kd; return g;
    };
    auto cvt = [&](const float* s, u16* hi, u16* lo, long n) {
        long n8 = n / 8;
        to_hilo<<<(int)((n8 + 255) / 256), 256, 0, stream>>>(s, hi, lo, n8);
    };

    if (fast) {
        hipMemsetAsync(hF_h[0], 0, (size_t)B_ * H_ * sizeof(u16), stream);
        hipMemsetAsync(hF_l[0], 0, (size_t)B_ * H_ * sizeof(u16), stream);
        prep_w48<H_, 32><<<1536, 256, 0, stream>>>(W_hh, whhF_h, whhF_l);
        prep_w48<D_, 16><<<768, 256, 0, stream>>>(W_ih, wihF_h, wihF_l);
        cvt(Wq,  wqR_h,  wqR_l,  (long)BN_ * H_);
        cvt(uW1, uw1R_h, uw1R_l, (long)H_ * (D_ + BN_));
        cvt(uW2, uw2R_h, uw2R_l, (long)H_ * H_);
        cvt(pW1, pw1R_h, pw1R_l, (long)H_ * BN_);
        cvt(pW2, pw2R_h, pw2R_l, (long)BN_ * H_);
        pack_x_all<<<2048, 256, 0, stream>>>(x, xF_h, xF_l);

        for (int w = 0; w < W_; ++w) {
            FS6 f;
            f.hFh_in = hF_h[w & 1];        f.hFl_in = hF_l[w & 1];
            f.hFh_out = hF_h[(w + 1) & 1]; f.hFl_out = hF_l[(w + 1) & 1];
            f.h_f32_out = (w == W_ - 1) ? hA : nullptr;
            f.WFh = whhF_h; f.WFl = whhF_l;
            f.XWh = wihF_h; f.XWl = wihF_l;
            f.xFh = xF_h + (long)w * 262144;
            f.xFl = xF_l + (long)w * 262144;
            f.b_hh = b_hh; f.b_ih = b_ih;
            gru_step9<<<512, 256, 0, stream>>>(f);
        }

        auto gemm = [&](int act, GArgs g, int N, int M) {
            dim3 grid(N / 64, M / 64);
            if (act == 1) hilo_gemm64<1, 1><<<grid, 256, 0, stream>>>(g);
            else          hilo_gemm64<0, 1><<<grid, 256, 0, stream>>>(g);
        };
        gemm(0, mkargs(hA, H_, Wq, wqR_h, wqR_l, bq, q, BN_, H_), BN_, B_);
        vq16<<<256, 256, 0, stream>>>(q, emb, e2, out + o_idx, idxi);
        gather_loss<<<(B_ * K_ * C_) / 256, 256, 0, stream>>>(
            q, emb, idxi, out + o_quant, out + o_narr, out + o_loss);
        build_uin<<<(B_ * (D_ + BN_)) / 256, 256, 0, stream>>>(x, out + o_narr, uin);
        gemm(1, mkargs(uin, D_ + BN_, uW1, uw1R_h, uw1R_l, ub1, mlph, H_, D_ + BN_), H_, B_);
        gemm(0, mkargs(mlph, H_, uW2, uw2R_h, uw2R_l, ub2, out + o_unc, H_, H_), H_, B_);
        gemm(1, mkargs(out + o_narr, BN_, pW1, pw1R_h, pw1R_l, pb1, t1, H_, BN_), H_, B_);
        gemm(0, mkargs(t1, H_, pW2, pw2R_h, pw2R_l, pb2, out + o_pred, BN_, H_), BN_, B_);
        copy_f<<<(B_ * H_) / 256, 256, 0, stream>>>(hA, out + o_lh);
        return;
    }

    // =============== legacy fallback (fp32-direct, any ws) ===============
    {
        GArgs g0 = mkargs(x, (long)W_ * D_, W_ih, 0, 0, b_ih, gibuf[0], G3, D_);
        hilo_gemm64<0, 0><<<dim3(48, 8), 256, 0, stream>>>(g0);
    }
    for (int w = 0; w < W_; ++w) {
        StepArgs s;
        s.h_in  = hbuf[w & 1];
        s.h_out = hbuf[(w + 1) & 1];
        s.W_hh = W_hh;
        s.gi = gibuf[w & 1];
        s.b_hh = b_hh;
        s.xw = (w + 1 < W_) ? (x + (long)(w + 1) * D_) : nullptr;
        s.W_ih = W_ih;
        s.b_ih = b_ih;
        s.gi_out = gibuf[(w + 1) & 1];
        gru_step2<<<640, 256, 0, stream>>>(s);
    }
    float* hfin = hbuf[0];

    auto gemmL = [&](int act, GArgs g, int N, int M) {
        dim3 grid(N / 64, M / 64);
        if (act == 1) hilo_gemm64<1, 0><<<grid, 256, 0, stream>>>(g);
        else          hilo_gemm64<0, 0><<<grid, 256, 0, stream>>>(g);
    };
    gemmL(0, mkargs(hfin, H_, Wq, 0, 0, bq, q, BN_, H_), BN_, B_);
    vq16<<<256, 256, 0, stream>>>(q, emb, e2, out + o_idx, idxi);
    gather_loss<<<(B_ * K_ * C_) / 256, 256, 0, stream>>>(
        q, emb, idxi, out + o_quant, out + o_narr, out + o_loss);
    build_uin<<<(B_ * (D_ + BN_)) / 256, 256, 0, stream>>>(x, out + o_narr, uin);
    gemmL(1, mkargs(uin, D_ + BN_, uW1, 0, 0, ub1, mlph, H_, D_ + BN_), H_, B_);
    gemmL(0, mkargs(mlph, H_, uW2, 0, 0, ub2, out + o_unc, H_, H_), H_, B_);
    gemmL(1, mkargs(out + o_narr, BN_, pW1, 0, 0, pb1, t1, H_, BN_), H_, B_);
    gemmL(0, mkargs(t1, H_, pW2, 0, 0, pb2, out + o_pred, BN_, H_), BN_, B_);
    copy_f<<<(B_ * H_) / 256, 256, 0, stream>>>(hfin, out + o_lh);
}

// Round 16
// 1689.784 us; speedup vs baseline: 1.0702x; 1.0702x over previous
//
#include <hip/hip_runtime.h>
#include <math.h>

#define B_ 512
#define W_ 64
#define D_ 512
#define H_ 1024
#define NC_ 1024
#define K_ 8
#define C_ 64
#define BN_ 512
#define G3 (3*H_)

typedef unsigned short u16;
typedef __attribute__((ext_vector_type(8))) short bf16x8;
typedef __attribute__((ext_vector_type(4))) float f32x4;

__device__ __forceinline__ float bf_up(u16 h) { return __uint_as_float(((unsigned)h) << 16); }
__device__ __forceinline__ u16 bf_rn(float x) {
    unsigned u = __float_as_uint(x);
    return (u16)((u + 0x7FFFu + ((u >> 16) & 1u)) >> 16);
}

__device__ __forceinline__ void split8v(float4 x, float4 y, uint4& H, uint4& L) {
    float v[8] = {x.x, x.y, x.z, x.w, y.x, y.y, y.z, y.w};
    union { u16 s[8]; uint4 u; } Hh, Ll;
    #pragma unroll
    for (int i = 0; i < 8; ++i) {
        unsigned ub = __float_as_uint(v[i]);
        u16 hi = (u16)(ub >> 16);
        Hh.s[i] = hi;
        Ll.s[i] = bf_rn(v[i] - bf_up(hi));
    }
    H = Hh.u; L = Ll.u;
}

__device__ __forceinline__ void cvt_store8(u16* ph, u16* pl, float4 x, float4 y) {
    uint4 H, L; split8v(x, y, H, L);
    *(uint4*)ph = H;
    *(uint4*)pl = L;
}

struct GArgs {
    const float* A;  long lda;
    const float* Bw;
    const u16* Bhi;  const u16* Blo;
    const float* bias;
    float* C;  long ldc;
    int K;
};

// ---- generic hi/lo GEMM (tail GEMMs + fallback), M64xN64, BK=32 ----
template<int ACT, int BPRE>
__device__ __forceinline__ void gemm_core64(const GArgs g, int bx, int by, u16* lds)
{
    u16* Ah = lds;
    u16* Al = lds + 2560;
    u16* Bh = lds + 5120;
    u16* Bl = lds + 7680;
    const int tid = threadIdx.x;
    const int l = tid & 63, wv = tid >> 6;
    const int m0 = by * 64, n0 = bx * 64;
    const int sr = tid >> 2, sc = (tid & 3) * 8;
    const int sA = sr * 40 + sc;

    const float* Ap = g.A + (long)(m0 + sr) * g.lda + sc;
    const float* Bp = 0; const u16 *Bph = 0, *Bpl = 0;
    if (BPRE) { Bph = g.Bhi + (long)(n0 + sr) * g.K + sc; Bpl = g.Blo + (long)(n0 + sr) * g.K + sc; }
    else      { Bp  = g.Bw  + (long)(n0 + sr) * g.K + sc; }

    f32x4 acc[4] = {};

    for (int k0 = 0; k0 < g.K; k0 += 32) {
        float4 a0 = *(const float4*)(Ap + k0);
        float4 a1 = *(const float4*)(Ap + k0 + 4);
        float4 b0, b1; uint4 h0, l0;
        if (BPRE) { h0 = *(const uint4*)(Bph + k0); l0 = *(const uint4*)(Bpl + k0); }
        else      { b0 = *(const float4*)(Bp + k0); b1 = *(const float4*)(Bp + k0 + 4); }
        __syncthreads();
        cvt_store8(Ah + sA, Al + sA, a0, a1);
        if (BPRE) { *(uint4*)(Bh + sA) = h0; *(uint4*)(Bl + sA) = l0; }
        else      { cvt_store8(Bh + sA, Bl + sA, b0, b1); }
        __syncthreads();

        const int fr = (l & 15) * 40 + (l >> 4) * 8;
        bf16x8 bh = *(const bf16x8*)(Bh + wv * 640 + fr);
        bf16x8 bl = *(const bf16x8*)(Bl + wv * 640 + fr);
        #pragma unroll
        for (int mt = 0; mt < 4; ++mt) {
            bf16x8 ah = *(const bf16x8*)(Ah + mt * 640 + fr);
            bf16x8 al = *(const bf16x8*)(Al + mt * 640 + fr);
            acc[mt] = __builtin_amdgcn_mfma_f32_16x16x32_bf16(ah, bh, acc[mt], 0, 0, 0);
            acc[mt] = __builtin_amdgcn_mfma_f32_16x16x32_bf16(ah, bl, acc[mt], 0, 0, 0);
            acc[mt] = __builtin_amdgcn_mfma_f32_16x16x32_bf16(al, bh, acc[mt], 0, 0, 0);
        }
    }

    const int n = n0 + wv * 16 + (l & 15);
    const float bv = g.bias[n];
    #pragma unroll
    for (int mt = 0; mt < 4; ++mt) {
        #pragma unroll
        for (int r = 0; r < 4; ++r) {
            int m = m0 + mt * 16 + (l >> 4) * 4 + r;
            float v = acc[mt][r] + bv;
            if (ACT == 1) v = v / (1.f + expf(-v));
            g.C[(long)m * g.ldc + n] = v;
        }
    }
}

template<int ACT, int BPRE>
__global__ __launch_bounds__(256)
void hilo_gemm64(GArgs g) {
    __shared__ u16 lds[10240];
    gemm_core64<ACT, BPRE>(g, blockIdx.x, blockIdx.y, lds);
}

// =================== fused GRU step, named-register pipeline (best: 1695 us) ===================
// Frag planes: plane[((frag*NKC + kc)*64 + lane)*8 + s], lane=(row&15)+((k&31)>>3)*16, s=k&7.
// 512 blocks x 256 thr. Tile 32m x 96n. Waves: mh=wv&1 (1 m-frag), nh=wv>>1 (48-col gate triple).
// Stages 0..15: gi (x@wih48, NKC=16). Stages 16..47: gh (h@whh48, NKC=32). Depth-2 reg pipeline.
struct FS6 {
    const u16* hFh_in; const u16* hFl_in;
    u16* hFh_out; u16* hFl_out;
    float* h_f32_out;                  // null except last step
    const u16* WFh; const u16* WFl;    // whh 48-perm frag, NKC=32
    const u16* XWh; const u16* XWl;    // wih 48-perm frag, NKC=16
    const u16* xFh; const u16* xFl;    // x slice w planes
    const float* b_hh; const float* b_ih;
};

__global__ __launch_bounds__(256)
void gru_step7(FS6 f)
{
    __shared__ u16 lds[16384];   // 2 x 8192 u16: [AH 1024 | AL 1024 | BH 3072 | BL 3072]
    const int tid = threadIdx.x, l = tid & 63, wv = tid >> 6;
    const int mh = wv & 1, nh = wv >> 1;
    const int by = blockIdx.x >> 5, bx = blockIdx.x & 31;

    // chunk 0: A (h or x); all 256 threads cover 2 mf x 2 planes x 64 lanes
    const int t0 = tid >> 6;
    const int mf0 = t0 & 1, pl0 = t0 >> 1;
    const u16* giP0 = (pl0 ? f.xFl : f.xFh) + (long)(by * 2 + mf0) * (16 * 512) + (long)l * 8;
    const u16* ghP0 = (pl0 ? f.hFl_in : f.hFh_in) + (long)(by * 2 + mf0) * (32 * 512) + (long)l * 8;
    const int lo0 = pl0 * 1024 + (mf0 * 64 + l) * 8;

    // chunks 1..3: B (weights); 768 thread-slots cover 6 nf x 2 planes x 64 lanes
    #define MKB_(c2, giP, ghP, lo) \
        { int lane_ = (c2) & 63, t_ = (c2) >> 6; int nf_ = t_ % 6, pl_ = t_ / 6; \
          giP = (pl_ ? f.XWl : f.XWh) + (long)(bx * 6 + nf_) * (16 * 512) + (long)lane_ * 8; \
          ghP = (pl_ ? f.WFl : f.WFh) + (long)(bx * 6 + nf_) * (32 * 512) + (long)lane_ * 8; \
          lo = 2048 + pl_ * 3072 + (nf_ * 64 + lane_) * 8; }
    const u16 *giP1, *ghP1, *giP2, *ghP2, *giP3, *ghP3;
    int lo1, lo2, lo3;
    MKB_(tid,       giP1, ghP1, lo1);
    MKB_(tid + 256, giP2, ghP2, lo2);
    MKB_(tid + 512, giP3, ghP3, lo3);
    #undef MKB_

    f32x4 gi0 = {}, gi1 = {}, gi2 = {}, gh0 = {}, gh1 = {}, gh2 = {};

    #define LDR7(st, R0, R1, R2, R3) { \
        if ((st) >= 16) { long ko = (long)((st) - 16) * 512; \
            R0 = *(const uint4*)(ghP0 + ko); R1 = *(const uint4*)(ghP1 + ko); \
            R2 = *(const uint4*)(ghP2 + ko); R3 = *(const uint4*)(ghP3 + ko); } \
        else { long ko = (long)(st) * 512; \
            R0 = *(const uint4*)(giP0 + ko); R1 = *(const uint4*)(giP1 + ko); \
            R2 = *(const uint4*)(giP2 + ko); R3 = *(const uint4*)(giP3 + ko); } }

    #define WRL7(bi, R0, R1, R2, R3) { u16* bb_ = lds + (bi) * 8192; \
        *(uint4*)(bb_ + lo0) = R0; *(uint4*)(bb_ + lo1) = R1; \
        *(uint4*)(bb_ + lo2) = R2; *(uint4*)(bb_ + lo3) = R3; }

    #define CMP7(st) { \
        const u16* bb_ = lds + ((st) & 1) * 8192; \
        bf16x8 ah  = *(const bf16x8*)(bb_ + (mh * 64 + l) * 8); \
        bf16x8 al  = *(const bf16x8*)(bb_ + 1024 + (mh * 64 + l) * 8); \
        bf16x8 b0h = *(const bf16x8*)(bb_ + 2048 + ((nh * 3 + 0) * 64 + l) * 8); \
        bf16x8 b1h = *(const bf16x8*)(bb_ + 2048 + ((nh * 3 + 1) * 64 + l) * 8); \
        bf16x8 b2h = *(const bf16x8*)(bb_ + 2048 + ((nh * 3 + 2) * 64 + l) * 8); \
        bf16x8 b0l = *(const bf16x8*)(bb_ + 5120 + ((nh * 3 + 0) * 64 + l) * 8); \
        bf16x8 b1l = *(const bf16x8*)(bb_ + 5120 + ((nh * 3 + 1) * 64 + l) * 8); \
        bf16x8 b2l = *(const bf16x8*)(bb_ + 5120 + ((nh * 3 + 2) * 64 + l) * 8); \
        if ((st) < 16) { \
            gi0 = __builtin_amdgcn_mfma_f32_16x16x32_bf16(ah, b0h, gi0, 0, 0, 0); \
            gi0 = __builtin_amdgcn_mfma_f32_16x16x32_bf16(ah, b0l, gi0, 0, 0, 0); \
            gi0 = __builtin_amdgcn_mfma_f32_16x16x32_bf16(al, b0h, gi0, 0, 0, 0); \
            gi1 = __builtin_amdgcn_mfma_f32_16x16x32_bf16(ah, b1h, gi1, 0, 0, 0); \
            gi1 = __builtin_amdgcn_mfma_f32_16x16x32_bf16(ah, b1l, gi1, 0, 0, 0); \
            gi1 = __builtin_amdgcn_mfma_f32_16x16x32_bf16(al, b1h, gi1, 0, 0, 0); \
            gi2 = __builtin_amdgcn_mfma_f32_16x16x32_bf16(ah, b2h, gi2, 0, 0, 0); \
            gi2 = __builtin_amdgcn_mfma_f32_16x16x32_bf16(ah, b2l, gi2, 0, 0, 0); \
            gi2 = __builtin_amdgcn_mfma_f32_16x16x32_bf16(al, b2h, gi2, 0, 0, 0); \
        } else { \
            gh0 = __builtin_amdgcn_mfma_f32_16x16x32_bf16(ah, b0h, gh0, 0, 0, 0); \
            gh0 = __builtin_amdgcn_mfma_f32_16x16x32_bf16(ah, b0l, gh0, 0, 0, 0); \
            gh0 = __builtin_amdgcn_mfma_f32_16x16x32_bf16(al, b0h, gh0, 0, 0, 0); \
            gh1 = __builtin_amdgcn_mfma_f32_16x16x32_bf16(ah, b1h, gh1, 0, 0, 0); \
            gh1 = __builtin_amdgcn_mfma_f32_16x16x32_bf16(ah, b1l, gh1, 0, 0, 0); \
            gh1 = __builtin_amdgcn_mfma_f32_16x16x32_bf16(al, b1h, gh1, 0, 0, 0); \
            gh2 = __builtin_amdgcn_mfma_f32_16x16x32_bf16(ah, b2h, gh2, 0, 0, 0); \
            gh2 = __builtin_amdgcn_mfma_f32_16x16x32_bf16(ah, b2l, gh2, 0, 0, 0); \
            gh2 = __builtin_amdgcn_mfma_f32_16x16x32_bf16(al, b2h, gh2, 0, 0, 0); \
        } }

    uint4 a0, a1, a2, a3, b0, b1, b2, b3;
    LDR7(0, a0, a1, a2, a3); WRL7(0, a0, a1, a2, a3);
    LDR7(1, a0, a1, a2, a3);
    LDR7(2, b0, b1, b2, b3);
    __syncthreads();
    #pragma unroll
    for (int s2 = 0; s2 < 48; s2 += 2) {
        CMP7(s2);
        if (s2 + 1 < 48) WRL7(1, a0, a1, a2, a3);
        if (s2 + 3 < 48) LDR7(s2 + 3, a0, a1, a2, a3);
        __syncthreads();
        CMP7(s2 + 1);
        if (s2 + 2 < 48) WRL7(0, b0, b1, b2, b3);
        if (s2 + 4 < 48) LDR7(s2 + 4, b0, b1, b2, b3);
        __syncthreads();
    }
    #undef LDR7
    #undef WRL7
    #undef CMP7

    // ---- fused GRU update epilogue ----
    const int mfG = by * 2 + mh;
    const int j = (bx * 2 + nh) * 16 + (l & 15);
    const float bir = f.b_ih[j], biz = f.b_ih[H_ + j], bin2 = f.b_ih[2 * H_ + j];
    const float bhr = f.b_hh[j], bhz = f.b_hh[H_ + j], bhn = f.b_hh[2 * H_ + j];
    const int kcj = j >> 5, laneTop = ((j >> 3) & 3) * 16, sj = j & 7;
    const long foB = ((long)(mfG * 32 + kcj) * 64) * 8 + sj;
    const bool wf32 = (f.h_f32_out != nullptr);
    #pragma unroll
    for (int r = 0; r < 4; ++r) {
        int mlow = (l >> 4) * 4 + r;          // m & 15
        long fo = foB + (long)(mlow + laneTop) * 8;
        float hprev = bf_up(f.hFh_in[fo]) + bf_up(f.hFl_in[fo]);
        float ir = gi0[r] + bir, iz = gi1[r] + biz, inn = gi2[r] + bin2;
        float hr = gh0[r] + bhr, hz = gh1[r] + bhz, hn = gh2[r] + bhn;
        float rg = 1.f / (1.f + expf(-(ir + hr)));
        float zg = 1.f / (1.f + expf(-(iz + hz)));
        float ng = tanhf(inn + rg * hn);
        float hv = (1.f - zg) * ng + zg * hprev;
        unsigned ub = __float_as_uint(hv);
        u16 hh = (u16)(ub >> 16);
        f.hFh_out[fo] = hh;
        f.hFl_out[fo] = bf_rn(hv - bf_up(hh));
        if (wf32) {
            int m = by * 32 + mh * 16 + mlow;
            f.h_f32_out[(long)m * H_ + j] = hv;
        }
    }
}

// ---------------- prep kernels ----------------
__global__ __launch_bounds__(256)
void to_hilo(const float* __restrict__ src, u16* __restrict__ hi, u16* __restrict__ lo, long n8) {
    long i = (long)blockIdx.x * 256 + threadIdx.x;
    if (i >= n8) return;
    float4 a = ((const float4*)src)[2 * i];
    float4 b = ((const float4*)src)[2 * i + 1];
    uint4 H, L; split8v(a, b, H, L);
    ((uint4*)hi)[i] = H;
    ((uint4*)lo)[i] = L;
}

// W [3H x KD] -> frag order with 48-perm: frag col p = nf*16+(l&15); src row = g*H + jg*16 + jl
template<int KD, int NKC>
__global__ __launch_bounds__(256)
void prep_w48(const float* __restrict__ W, u16* __restrict__ fh, u16* __restrict__ fl)
{
    long t = (long)blockIdx.x * 256 + threadIdx.x;   // 192*NKC*64 total
    if (t >= (long)192 * NKC * 64) return;
    int l = (int)(t & 63);
    long nk = t >> 6;
    int kc = (int)(nk % NKC);
    int nf = (int)(nk / NKC);
    int p = nf * 16 + (l & 15);
    int jg = p / 48, g = (p % 48) >> 4, jl = p & 15;
    int srow = g * H_ + jg * 16 + jl;
    int k0 = kc * 32 + (l >> 4) * 8;
    float4 v0 = *(const float4*)(W + (long)srow * KD + k0);
    float4 v1 = *(const float4*)(W + (long)srow * KD + k0 + 4);
    uint4 H, L; split8v(v0, v1, H, L);
    ((uint4*)fh)[t] = H;
    ((uint4*)fl)[t] = L;
}

// pack ALL x slices: x[b][w][d] fp32 -> per-slice frag planes (slice stride 262144 elems)
__global__ __launch_bounds__(256)
void pack_x_all(const float* __restrict__ x, u16* __restrict__ dh, u16* __restrict__ dl)
{
    #pragma unroll
    for (int it = 0; it < 4; ++it) {
        long e4 = (long)blockIdx.x * 1024 + it * 256 + threadIdx.x;  // 4,194,304 total
        int b  = (int)(e4 >> 13);
        int rem = (int)(e4 & 8191);
        int w  = rem >> 7;
        int dd = (rem & 127) * 4;
        float4 v = *(const float4*)(x + (long)b * (W_ * D_) + (long)w * D_ + dd);
        union { u16 s[4]; uint2 u; } Hh, Ll;
        float vv[4] = {v.x, v.y, v.z, v.w};
        #pragma unroll
        for (int i = 0; i < 4; ++i) {
            unsigned ub = __float_as_uint(vv[i]);
            u16 hi = (u16)(ub >> 16);
            Hh.s[i] = hi;
            Ll.s[i] = bf_rn(vv[i] - bf_up(hi));
        }
        int mf = b >> 4, kc = dd >> 5;
        int lane = (b & 15) + ((dd >> 3) & 3) * 16;
        long fo = (long)w * 262144 + ((long)(mf * 16 + kc) * 64 + lane) * 8 + (dd & 7);
        *(uint2*)(dh + fo) = Hh.u;
        *(uint2*)(dl + fo) = Ll.u;
    }
}

// =================== legacy fallback (fp32-direct) ===================
struct StepArgs {
    const float* h_in;  float* h_out;
    const float* W_hh;
    const float* gi;
    const float* b_hh;
    const float* xw;
    const float* W_ih;
    const float* b_ih;
    float* gi_out;
};

__global__ __launch_bounds__(256)
void gru_step2(StepArgs s)
{
    __shared__ u16 lds[17920];
    const int id = blockIdx.x;
    const int tid = threadIdx.x;
    if (id >= 256) {
        if (!s.xw) return;
        int id2 = id - 256;
        GArgs g;
        g.A = s.xw; g.lda = (long)W_ * D_;
        g.Bw = s.W_ih; g.Bhi = 0; g.Blo = 0;
        g.bias = s.b_ih; g.C = s.gi_out; g.ldc = G3; g.K = D_;
        gemm_core64<0, 0>(g, id2 % 48, id2 / 48, lds);
        return;
    }
    u16* Ah = lds;
    u16* Al = lds + 1280;
    u16* Bh = lds + 2560;
    u16* Bl = lds + 10240;
    const int by = id >> 4, bx = id & 15;
    const int l = tid & 63, wv = tid >> 6;
    const int m0 = by * 32, j0 = bx * 64;
    const int sr = tid >> 2, sc = (tid & 3) * 8;
    const int sA = sr * 40 + sc;

    const float* Ap = s.h_in + (long)(m0 + (tid >> 2)) * H_ + sc;

    f32x4 acc[2][3] = {};

    for (int k0 = 0; k0 < H_; k0 += 32) {
        float4 a0, a1;
        if (tid < 128) {
            a0 = *(const float4*)(Ap + k0);
            a1 = *(const float4*)(Ap + k0 + 4);
        }
        float4 bf0[3], bf1[3];
        #pragma unroll
        for (int g = 0; g < 3; ++g) {
            long rowp = (long)(g * H_ + j0 + sr);
            bf0[g] = *(const float4*)(s.W_hh + rowp * H_ + k0 + sc);
            bf1[g] = *(const float4*)(s.W_hh + rowp * H_ + k0 + sc + 4);
        }
        __syncthreads();
        if (tid < 128) cvt_store8(Ah + sA, Al + sA, a0, a1);
        #pragma unroll
        for (int g = 0; g < 3; ++g)
            cvt_store8(Bh + g * 2560 + sA, Bl + g * 2560 + sA, bf0[g], bf1[g]);
        __syncthreads();

        const int fr = (l & 15) * 40 + (l >> 4) * 8;
        bf16x8 bhf[3], blf[3];
        #pragma unroll
        for (int g = 0; g < 3; ++g) {
            bhf[g] = *(const bf16x8*)(Bh + g * 2560 + wv * 640 + fr);
            blf[g] = *(const bf16x8*)(Bl + g * 2560 + wv * 640 + fr);
        }
        #pragma unroll
        for (int mt = 0; mt < 2; ++mt) {
            bf16x8 ah = *(const bf16x8*)(Ah + mt * 640 + fr);
            bf16x8 al = *(const bf16x8*)(Al + mt * 640 + fr);
            #pragma unroll
            for (int g = 0; g < 3; ++g) {
                acc[mt][g] = __builtin_amdgcn_mfma_f32_16x16x32_bf16(ah, bhf[g], acc[mt][g], 0, 0, 0);
                acc[mt][g] = __builtin_amdgcn_mfma_f32_16x16x32_bf16(ah, blf[g], acc[mt][g], 0, 0, 0);
                acc[mt][g] = __builtin_amdgcn_mfma_f32_16x16x32_bf16(al, bhf[g], acc[mt][g], 0, 0, 0);
            }
        }
    }

    const int j = j0 + wv * 16 + (l & 15);
    const float bhr = s.b_hh[j], bhz = s.b_hh[H_ + j], bhn = s.b_hh[2 * H_ + j];
    #pragma unroll
    for (int mt = 0; mt < 2; ++mt) {
        #pragma unroll
        for (int r = 0; r < 4; ++r) {
            int m = m0 + mt * 16 + (l >> 4) * 4 + r;
            const float* gib = s.gi + (long)m * G3;
            float ir = gib[j], iz = gib[H_ + j], inn = gib[2 * H_ + j];
            float hr = acc[mt][0][r] + bhr;
            float hz = acc[mt][1][r] + bhz;
            float hn = acc[mt][2][r] + bhn;
            float rg = 1.f / (1.f + expf(-(ir + hr)));
            float zg = 1.f / (1.f + expf(-(iz + hz)));
            float ng = tanhf(inn + rg * hn);
            s.h_out[(long)m * H_ + j] = (1.f - zg) * ng + zg * s.h_in[(long)m * H_ + j];
        }
    }
}

// ---------------- misc small kernels ----------------
__global__ void emb_norm(const float* __restrict__ emb, float* __restrict__ e2,
                         float* __restrict__ loss_slot)
{
    int n = blockIdx.x * 256 + threadIdx.x;
    if (n == 0) *loss_slot = 0.f;
    if (n < NC_) {
        const float4* e4 = (const float4*)(emb + (long)n * C_);
        float s = 0.f;
        #pragma unroll
        for (int c = 0; c < 16; ++c) { float4 e = e4[c]; s += e.x*e.x + e.y*e.y + e.z*e.z + e.w*e.w; }
        e2[n] = s;
    }
}

__global__ __launch_bounds__(256)
void vq16(const float* __restrict__ q, const float* __restrict__ emb,
          const float* __restrict__ e2, float* __restrict__ out_f,
          int* __restrict__ out_i)
{
    __shared__ float es[128 * 68];
    const int blk = blockIdx.x, tid = threadIdx.x;
    const int qg = tid >> 4, sI = tid & 15;
    float4 qr[16];
    {
        const float4* qrow = (const float4*)(q + (long)(blk * 16 + qg) * C_);
        #pragma unroll
        for (int i = 0; i < 16; ++i) qr[i] = qrow[i];
    }
    float bestv = 3.4e38f; int besti = 0;

    for (int n0 = 0; n0 < NC_; n0 += 128) {
        __syncthreads();
        const float4* e4 = (const float4*)(emb + (long)n0 * C_);
        #pragma unroll
        for (int i = tid; i < 2048; i += 256) {
            int code = i >> 4, c4 = i & 15;
            *(float4*)(es + code * 68 + c4 * 4) = e4[i];
        }
        __syncthreads();
        #pragma unroll
        for (int jj = 0; jj < 8; ++jj) {
            int code = sI + 16 * jj;
            const float* er = es + code * 68;
            float dot = 0.f;
            #pragma unroll
            for (int c4 = 0; c4 < 16; ++c4) {
                float4 ev = *(const float4*)(er + c4 * 4);
                dot += ev.x * qr[c4].x + ev.y * qr[c4].y + ev.z * qr[c4].z + ev.w * qr[c4].w;
            }
            float d = e2[n0 + code] - 2.f * dot;
            if (d < bestv) { bestv = d; besti = n0 + code; }
        }
    }
    #pragma unroll
    for (int m = 1; m <= 8; m <<= 1) {
        float ov = __shfl_xor(bestv, m);
        int   oi = __shfl_xor(besti, m);
        if (ov < bestv || (ov == bestv && oi < besti)) { bestv = ov; besti = oi; }
    }
    if (sI == 0) {
        int bk = blk * 16 + qg;
        out_f[bk] = (float)besti;
        out_i[bk] = besti;
    }
}

__global__ __launch_bounds__(256)
void gather_loss(const float* __restrict__ q, const float* __restrict__ emb,
                 const int* __restrict__ idx, float* __restrict__ quant_out,
                 float* __restrict__ narr_out, float* __restrict__ loss_slot)
{
    int i = blockIdx.x * 256 + threadIdx.x;
    int bk = i >> 6;
    int c  = i & 63;
    float e  = emb[(long)idx[bk] * C_ + c];
    float qv = q[i];
    quant_out[i] = e;
    narr_out[i]  = e;
    float dsq = (qv - e) * (qv - e);
    __shared__ float red[256];
    red[threadIdx.x] = dsq;
    __syncthreads();
    for (int s = 128; s > 0; s >>= 1) {
        if (threadIdx.x < s) red[threadIdx.x] += red[threadIdx.x + s];
        __syncthreads();
    }
    if (threadIdx.x == 0)
        atomicAdd(loss_slot, red[0] * (1.25f / (float)(B_ * K_ * C_)));
}

__global__ __launch_bounds__(256)
void build_uin(const float* __restrict__ x, const float* __restrict__ narr,
               float* __restrict__ uin)
{
    int i = blockIdx.x * 256 + threadIdx.x;
    int b = i >> 10;
    int j = i & 1023;
    uin[i] = (j < D_) ? x[(long)b * W_ * D_ + (long)(W_ - 1) * D_ + j]
                      : narr[(long)b * BN_ + (j - D_)];
}

__global__ __launch_bounds__(256)
void copy_f(const float* __restrict__ src, float* __restrict__ dst)
{
    int i = blockIdx.x * 256 + threadIdx.x;
    dst[i] = src[i];
}

extern "C" void kernel_launch(void* const* d_in, const int* in_sizes, int n_in,
                              void* d_out, int out_size, void* d_ws, size_t ws_size,
                              hipStream_t stream)
{
    (void)in_sizes; (void)n_in; (void)out_size;
    const float* x     = (const float*)d_in[0];
    const float* W_ih  = (const float*)d_in[1];
    const float* W_hh  = (const float*)d_in[2];
    const float* b_ih  = (const float*)d_in[3];
    const float* b_hh  = (const float*)d_in[4];
    const float* Wq    = (const float*)d_in[5];
    const float* bq    = (const float*)d_in[6];
    const float* emb   = (const float*)d_in[7];
    const float* uW1   = (const float*)d_in[8];
    const float* ub1   = (const float*)d_in[9];
    const float* uW2   = (const float*)d_in[10];
    const float* ub2   = (const float*)d_in[11];
    const float* pW1   = (const float*)d_in[12];
    const float* pb1   = (const float*)d_in[13];
    const float* pW2   = (const float*)d_in[14];
    const float* pb2   = (const float*)d_in[15];

    float* ws = (float*)d_ws;
    float* hA   = ws;                       // 524288
    float* giA  = ws + 524288;              // 1572864 (fallback only)
    float* giB  = ws + 2097152;             // 1572864 (fallback only)
    float* q    = ws + 3670016;             // 262144
    float* e2   = ws + 3932160;             // 1024
    int*   idxi = (int*)(ws + 3933184);     // 4096
    const long FLOAT_WORDS = 3937280;
    float* uin  = giB;
    float* mlph = giB + 524288;
    float* t1   = giA;

    u16* wsu = (u16*)((char*)d_ws + FLOAT_WORDS * sizeof(float));
    // frag-ordered GRU weights (48-perm)
    u16* whhF_h = wsu;             u16* whhF_l = wsu + 3145728;
    u16* wihF_h = wsu + 6291456;   u16* wihF_l = wsu + 7864320;
    // row-major tail weights
    u16* wqR_h  = wsu + 9437184;   u16* wqR_l  = wsu + 9961472;
    u16* uw1R_h = wsu + 10485760;  u16* uw1R_l = wsu + 11534336;
    u16* uw2R_h = wsu + 12582912;  u16* uw2R_l = wsu + 13631488;
    u16* pw1R_h = wsu + 14680064;  u16* pw1R_l = wsu + 15204352;
    u16* pw2R_h = wsu + 15728640;  u16* pw2R_l = wsu + 16252928;
    // h frag planes (ping-pong)
    u16* hF_h[2] = { wsu + 16777216, wsu + 17301504 };
    u16* hF_l[2] = { wsu + 17825792, wsu + 18350080 };
    // x frag planes, all 64 slices
    u16* xF_h = wsu + 18874368;    // 16777216
    u16* xF_l = wsu + 35651584;    // 16777216
    const size_t NEED_NEW = FLOAT_WORDS * sizeof(float) + (size_t)52428800 * 2;
    const bool fast = ws_size >= NEED_NEW;

    float* out = (float*)d_out;
    const long o_idx   = 0;
    const long o_quant = o_idx   + (long)B_ * K_;
    const long o_narr  = o_quant + (long)B_ * K_ * C_;
    const long o_unc   = o_narr  + (long)B_ * BN_;
    const long o_pred  = o_unc   + (long)B_ * H_;
    const long o_loss  = o_pred  + (long)B_ * BN_;
    const long o_lh    = o_loss  + 1;

    float* hB = out + o_unc;                 // fallback ping-pong only
    float* hbuf[2] = { hA, hB };
    float* gibuf[2] = { giA, giB };

    hipMemsetAsync(hA, 0, (size_t)B_ * H_ * sizeof(float), stream);
    emb_norm<<<4, 256, 0, stream>>>(emb, e2, out + o_loss);

    auto mkargs = [&](const float* A, long lda, const float* Bw, const u16* Bh, const u16* Bl,
                      const float* bias, float* C, long ldc, int Kd) {
        GArgs g; g.A = A; g.lda = lda; g.Bw = Bw; g.Bhi = Bh; g.Blo = Bl;
        g.bias = bias; g.C = C; g.ldc = ldc; g.K = Kd; return g;
    };
    auto cvt = [&](const float* s, u16* hi, u16* lo, long n) {
        long n8 = n / 8;
        to_hilo<<<(int)((n8 + 255) / 256), 256, 0, stream>>>(s, hi, lo, n8);
    };

    if (fast) {
        hipMemsetAsync(hF_h[0], 0, (size_t)B_ * H_ * sizeof(u16), stream);
        hipMemsetAsync(hF_l[0], 0, (size_t)B_ * H_ * sizeof(u16), stream);
        prep_w48<H_, 32><<<1536, 256, 0, stream>>>(W_hh, whhF_h, whhF_l);
        prep_w48<D_, 16><<<768, 256, 0, stream>>>(W_ih, wihF_h, wihF_l);
        cvt(Wq,  wqR_h,  wqR_l,  (long)BN_ * H_);
        cvt(uW1, uw1R_h, uw1R_l, (long)H_ * (D_ + BN_));
        cvt(uW2, uw2R_h, uw2R_l, (long)H_ * H_);
        cvt(pW1, pw1R_h, pw1R_l, (long)H_ * BN_);
        cvt(pW2, pw2R_h, pw2R_l, (long)BN_ * H_);
        pack_x_all<<<4096, 256, 0, stream>>>(x, xF_h, xF_l);

        for (int w = 0; w < W_; ++w) {
            FS6 f;
            f.hFh_in = hF_h[w & 1];        f.hFl_in = hF_l[w & 1];
            f.hFh_out = hF_h[(w + 1) & 1]; f.hFl_out = hF_l[(w + 1) & 1];
            f.h_f32_out = (w == W_ - 1) ? hA : nullptr;
            f.WFh = whhF_h; f.WFl = whhF_l;
            f.XWh = wihF_h; f.XWl = wihF_l;
            f.xFh = xF_h + (long)w * 262144;
            f.xFl = xF_l + (long)w * 262144;
            f.b_hh = b_hh; f.b_ih = b_ih;
            gru_step7<<<512, 256, 0, stream>>>(f);
        }

        auto gemm = [&](int act, GArgs g, int N, int M) {
            dim3 grid(N / 64, M / 64);
            if (act == 1) hilo_gemm64<1, 1><<<grid, 256, 0, stream>>>(g);
            else          hilo_gemm64<0, 1><<<grid, 256, 0, stream>>>(g);
        };
        gemm(0, mkargs(hA, H_, Wq, wqR_h, wqR_l, bq, q, BN_, H_), BN_, B_);
        vq16<<<256, 256, 0, stream>>>(q, emb, e2, out + o_idx, idxi);
        gather_loss<<<(B_ * K_ * C_) / 256, 256, 0, stream>>>(
            q, emb, idxi, out + o_quant, out + o_narr, out + o_loss);
        build_uin<<<(B_ * (D_ + BN_)) / 256, 256, 0, stream>>>(x, out + o_narr, uin);
        gemm(1, mkargs(uin, D_ + BN_, uW1, uw1R_h, uw1R_l, ub1, mlph, H_, D_ + BN_), H_, B_);
        gemm(0, mkargs(mlph, H_, uW2, uw2R_h, uw2R_l, ub2, out + o_unc, H_, H_), H_, B_);
        gemm(1, mkargs(out + o_narr, BN_, pW1, pw1R_h, pw1R_l, pb1, t1, H_, BN_), H_, B_);
        gemm(0, mkargs(t1, H_, pW2, pw2R_h, pw2R_l, pb2, out + o_pred, BN_, H_), BN_, B_);
        copy_f<<<(B_ * H_) / 256, 256, 0, stream>>>(hA, out + o_lh);
        return;
    }

    // =============== legacy fallback (fp32-direct, any ws) ===============
    {
        GArgs g0 = mkargs(x, (long)W_ * D_, W_ih, 0, 0, b_ih, gibuf[0], G3, D_);
        hilo_gemm64<0, 0><<<dim3(48, 8), 256, 0, stream>>>(g0);
    }
    for (int w = 0; w < W_; ++w) {
        StepArgs s;
        s.h_in  = hbuf[w & 1];
        s.h_out = hbuf[(w + 1) & 1];
        s.W_hh = W_hh;
        s.gi = gibuf[w & 1];
        s.b_hh = b_hh;
        s.xw = (w + 1 < W_) ? (x + (long)(w + 1) * D_) : nullptr;
        s.W_ih = W_ih;
        s.b_ih = b_ih;
        s.gi_out = gibuf[(w + 1) & 1];
        gru_step2<<<640, 256, 0, stream>>>(s);
    }
    float* hfin = hbuf[0];

    auto gemmL = [&](int act, GArgs g, int N, int M) {
        dim3 grid(N / 64, M / 64);
        if (act == 1) hilo_gemm64<1, 0><<<grid, 256, 0, stream>>>(g);
        else          hilo_gemm64<0, 0><<<grid, 256, 0, stream>>>(g);
    };
    gemmL(0, mkargs(hfin, H_, Wq, 0, 0, bq, q, BN_, H_), BN_, B_);
    vq16<<<256, 256, 0, stream>>>(q, emb, e2, out + o_idx, idxi);
    gather_loss<<<(B_ * K_ * C_) / 256, 256, 0, stream>>>(
        q, emb, idxi, out + o_quant, out + o_narr, out + o_loss);
    build_uin<<<(B_ * (D_ + BN_)) / 256, 256, 0, stream>>>(x, out + o_narr, uin);
    gemmL(1, mkargs(uin, D_ + BN_, uW1, 0, 0, ub1, mlph, H_, D_ + BN_), H_, B_);
    gemmL(0, mkargs(mlph, H_, uW2, 0, 0, ub2, out + o_unc, H_, H_), H_, B_);
    gemmL(1, mkargs(out + o_narr, BN_, pW1, 0, 0, pb1, t1, H_, BN_), H_, B_);
    gemmL(0, mkargs(t1, H_, pW2, 0, 0, pb2, out + o_pred, BN_, H_), BN_, B_);
    copy_f<<<(B_ * H_) / 256, 256, 0, stream>>>(hfin, out + o_lh);
}